// Round 10
// baseline (285.050 us; speedup 1.0000x reference)
//
#include <hip/hip_runtime.h>

// HybridQLSTMQuantum, MI355X — v10.
//   K1: GEMM with explicit 2-deep row software pipeline (named xa/xb bufs).
//   K2: recurrence; A staged through LDS via global_load_lds (compiler
//       cannot sink it — R9's register prefetch was DCE'd/sunk: VGPR=56
//       proved the 8 float4s never stayed live). Pade(5,4) tanh for c.
//
// qgate identity (verified analytically):
//   qgate(angles)[w] = prod_{j<=w} cos(angles[j])
//
// v6 single-kernel fallback retained for small ws.

#define S_LEN 256
#define BATCH 256
#define DIMK  256
#define FAN   264
#define NROWS (S_LEN * BATCH)
#define WS_NEED ((size_t)NROWS * 32 * 4)

typedef __attribute__((address_space(1))) const void GV;
typedef __attribute__((address_space(3))) void LV;

__device__ __forceinline__ float lo16f(unsigned u) {
    union { unsigned u; float f; } v; v.u = u << 16; return v.f;
}
__device__ __forceinline__ float hi16f(unsigned u) {
    union { unsigned u; float f; } v; v.u = u & 0xffff0000u; return v.f;
}
__device__ __forceinline__ float b2f(unsigned short u) {
    union { unsigned u; float f; } v; v.u = ((unsigned)u) << 16; return v.f;
}
__device__ __forceinline__ unsigned short f2b(float f) {
    union { float f; unsigned u; } v; v.f = f;
    unsigned r = v.u + 0x7fffu + ((v.u >> 16) & 1u);  // RNE
    return (unsigned short)(r >> 16);
}
__device__ __forceinline__ float sane(float x) {
    return (__builtin_fabsf(x) < 1e30f) ? x : 0.f;   // NaN compares false -> 0
}
__device__ __forceinline__ float ldE(const void* p, int idx, bool f32) {
    return f32 ? ((const float*)p)[idx] : b2f(((const unsigned short*)p)[idx]);
}
__device__ __forceinline__ void stE(void* p, long idx, float v, bool f32) {
    if (f32) ((float*)p)[idx] = v;
    else     ((unsigned short*)p)[idx] = f2b(v);
}
// poly sigmoid on [-1,1]: err<=1e-4 (R9-verified)
__device__ __forceinline__ float sigp(float x) {
    float x2 = x * x;
    float p = fmaf(x2, 0.0026216f, -0.0217557f);
    p = fmaf(x2, p, 0.250193f);
    return fmaf(x, p, 0.5f);
}
// poly tanh on [-1,1]: err<=2e-4 (R9-verified)
__device__ __forceinline__ float tanp(float x) {
    float x2 = x * x;
    float p = fmaf(x2, -0.028402f, 0.121713f);
    p = fmaf(x2, p, -0.331717f);
    return x * fmaf(x2, p, 1.0f);
}
// Pade(5,4) tanh: x(945+105x^2+x^4)/(945+420x^2+15x^4); err<=1e-4 for |x|<=2.2
__device__ __forceinline__ float tanh_pade(float x) {
    float x2 = x * x;
    float num = x * fmaf(x2, x2 + 105.f, 945.f);
    float den = fmaf(x2, fmaf(x2, 15.f, 420.f), 945.f);
    return __fdividef(num, den);
}
__device__ __forceinline__ float tanh_f(float x) {   // exp-based (fallback kernel)
    return 1.f - __fdividef(2.f, __expf(2.f * x) + 1.f);
}

// DPP: 0x00-0xFF quad_perm; 0x110|K row_shr:K; 0x141 row_half_mirror.
template<int CTRL>
__device__ __forceinline__ float dpp_f(float x) {
    int xi = __builtin_bit_cast(int, x);
    int r = __builtin_amdgcn_update_dpp(xi, xi, CTRL, 0xF, 0xF, false);
    return __builtin_bit_cast(float, r);
}
template<int IMM>
__device__ __forceinline__ float swz_f(float x) {
    return __builtin_bit_cast(float,
        __builtin_amdgcn_ds_swizzle(__builtin_bit_cast(int, x), IMM));
}
__device__ __forceinline__ float rdlane_f(float x, int l) {
    return __builtin_bit_cast(float,
        __builtin_amdgcn_readlane(__builtin_bit_cast(int, x), l));
}

__device__ __forceinline__ int sniff_f32(const void* X) {
    const unsigned short* u = (const unsigned short*)X;
    int hits = 0;
    for (int i = 0; i < 64; ++i) {
        int e = (u[2 * i] >> 7) & 0xFF;
        if (e >= 110 && e <= 135) ++hits;
    }
    return (hits < 32) ? 1 : 0;
}

// ============================ K1: GEMM -> ws ============================
// 512 thr = 8 waves; wave kv owns k in [kv*32, kv*32+32). Explicit 2-deep
// row pipeline (xa/xb named buffers): row j+1's 8 loads issued before row
// j's FMAs. VGPR ~ wreg(32)+xa(32)+xb(32)+misc ~ 110 < 128 cap of (512,4).
__global__ __launch_bounds__(512, 4) void qlstm_gemm(
    const void* __restrict__ X,
    const void* __restrict__ Wf, const void* __restrict__ Wi,
    const void* __restrict__ Wu, const void* __restrict__ Wo,
    float* __restrict__ A)
{
    __shared__ float red[8][64][32];   // 64 KiB k-partials

    const int tid = threadIdx.x;
    const bool f32 = sniff_f32(X) != 0;

    const int kv = tid >> 6;        // wave = k-slice (0..7)
    const int l  = tid & 63;
    const int o  = l & 31;
    const int th = l >> 5;          // row-half
    const int g  = o >> 3, w = o & 7;
    const void* Wg = (g == 0) ? Wf : (g == 1) ? Wi : (g == 2) ? Wu : Wo;

    float4 wreg[8];
    if (f32) {
        const float4* wr = (const float4*)((const float*)Wg + w * FAN + kv * 32);
#pragma unroll
        for (int i = 0; i < 8; ++i) wreg[i] = wr[i];
    } else {
        const uint4* wr = (const uint4*)((const unsigned short*)Wg + w * FAN + kv * 32);
#pragma unroll
        for (int i = 0; i < 4; ++i) {
            uint4 wu = wr[i];
            wreg[2 * i + 0] = make_float4(lo16f(wu.x), hi16f(wu.x),
                                          lo16f(wu.y), hi16f(wu.y));
            wreg[2 * i + 1] = make_float4(lo16f(wu.z), hi16f(wu.z),
                                          lo16f(wu.w), hi16f(wu.w));
        }
    }

    const long rowbase = (long)blockIdx.x * 64;   // rows = b*256 + t
    const int  rb      = th * 32;                 // this half's local row base

    if (f32) {
        auto xaddr = [&](int j) {
            const long row = rowbase + rb + j;
            const int t = (int)(row & 255), bb = (int)(row >> 8);
            return (const float4*)((const float*)X
                    + ((long)t * BATCH + bb) * DIMK + kv * 32);
        };
        auto dot = [&](const float4* xu) {
            float a0 = 0.f, a1 = 0.f, a2 = 0.f, a3 = 0.f;
#pragma unroll
            for (int i = 0; i < 8; ++i) {
                a0 = fmaf(xu[i].x, wreg[i].x, a0);
                a1 = fmaf(xu[i].y, wreg[i].y, a1);
                a2 = fmaf(xu[i].z, wreg[i].z, a2);
                a3 = fmaf(xu[i].w, wreg[i].w, a3);
            }
            return (a0 + a1) + (a2 + a3);
        };
        float4 xa[8], xb[8];
        { const float4* p = xaddr(0);
#pragma unroll
          for (int i = 0; i < 8; ++i) xa[i] = p[i]; }
        for (int j = 0; j < 32; j += 2) {
            { const float4* p = xaddr(j + 1);
#pragma unroll
              for (int i = 0; i < 8; ++i) xb[i] = p[i]; }
            red[kv][rb + j][o] = dot(xa);
            if (j + 2 < 32) {
                const float4* p = xaddr(j + 2);
#pragma unroll
                for (int i = 0; i < 8; ++i) xa[i] = p[i];
            }
            red[kv][rb + j + 1][o] = dot(xb);
        }
    } else {
        auto xaddr = [&](int j) {
            const long row = rowbase + rb + j;
            const int t = (int)(row & 255), bb = (int)(row >> 8);
            return (const uint4*)((const unsigned short*)X
                    + ((long)t * BATCH + bb) * DIMK + kv * 32);
        };
        auto dot = [&](const uint4* xu) {
            float a0 = 0.f, a1 = 0.f, a2 = 0.f, a3 = 0.f;
#pragma unroll
            for (int i = 0; i < 4; ++i) {
                a0 = fmaf(lo16f(xu[i].x), wreg[2 * i].x, a0);
                a1 = fmaf(hi16f(xu[i].x), wreg[2 * i].y, a1);
                a2 = fmaf(lo16f(xu[i].y), wreg[2 * i].z, a2);
                a3 = fmaf(hi16f(xu[i].y), wreg[2 * i].w, a3);
                a0 = fmaf(lo16f(xu[i].z), wreg[2 * i + 1].x, a0);
                a1 = fmaf(hi16f(xu[i].z), wreg[2 * i + 1].y, a1);
                a2 = fmaf(lo16f(xu[i].w), wreg[2 * i + 1].z, a2);
                a3 = fmaf(hi16f(xu[i].w), wreg[2 * i + 1].w, a3);
            }
            return (a0 + a1) + (a2 + a3);
        };
        uint4 xa[4], xb[4];
        { const uint4* p = xaddr(0);
#pragma unroll
          for (int i = 0; i < 4; ++i) xa[i] = p[i]; }
        for (int j = 0; j < 32; j += 2) {
            { const uint4* p = xaddr(j + 1);
#pragma unroll
              for (int i = 0; i < 4; ++i) xb[i] = p[i]; }
            red[kv][rb + j][o] = dot(xa);
            if (j + 2 < 32) {
                const uint4* p = xaddr(j + 2);
#pragma unroll
                for (int i = 0; i < 4; ++i) xa[i] = p[i];
            }
            red[kv][rb + j + 1][o] = dot(xb);
        }
    }
    __syncthreads();
    for (int idx = tid; idx < 64 * 32; idx += 512) {
        const int rl = idx >> 5, oo = idx & 31;
        float s = 0.f;
#pragma unroll
        for (int k = 0; k < 8; ++k) s += red[k][rl][oo];
        // repack: column = w*4 + g  (K2 reads one float4 per (b,t,w))
        A[(rowbase + rl) * 32 + (oo & 7) * 4 + (oo >> 3)] = sane(s);
    }
}

// ========================= K2: recurrence =========================
// 64 blocks x 64 thr; wave = 4 b-rows x 16 lanes (w x dup).
// A staged via global_load_lds into a 2x32KB LDS double buffer (4 chunks of
// 64 t); chunk ch+1's loads issued before chunk ch's steps -> ~20us of
// compute covers ~1us of flight. Per step: ds_read float4 + DPP cross-lane +
// poly gates + Pade tanh(c). No trans chain except cos.
__global__ __launch_bounds__(64) void qlstm_rec(
    const void* __restrict__ X,  const void* __restrict__ hx, const void* __restrict__ cx,
    const void* __restrict__ Wf, const void* __restrict__ bf_,
    const void* __restrict__ Wi, const void* __restrict__ bi_,
    const void* __restrict__ Wu, const void* __restrict__ bu_,
    const void* __restrict__ Wo, const void* __restrict__ bo_,
    const void* __restrict__ tf, const void* __restrict__ ti,
    const void* __restrict__ tu, const void* __restrict__ to_,
    void* __restrict__ out, const float* __restrict__ A)
{
    __shared__ float4 Abuf[2][2048];   // 64 KiB: [buf][t_loc*32 + bsub*8 + w]

    const int tid = threadIdx.x;
    const bool f32 = sniff_f32(X) != 0;

    const int p     = tid & 15;        // position in 16-lane row (one b)
    const int w     = p & 7;           // wire
    const int dup   = p >> 3;          // redundant half
    const int bsub  = tid >> 4;        // 0..3
    const int bglob = blockIdx.x * 4 + bsub;

    const void* Wg_[4] = { Wf, Wi, Wu, Wo };
    const void* bg_[4] = { bf_, bi_, bu_, bo_ };
    const void* tg_[4] = { tf, ti, tu, to_ };

    float Whm[4][8], bt[4];
#pragma unroll
    for (int g = 0; g < 4; ++g) {
#pragma unroll
        for (int m = 0; m < 8; ++m)
            Whm[g][m] = sane(ldE(Wg_[g], w * FAN + DIMK + (w ^ m), f32));
        bt[g] = sane(ldE(bg_[g], w, f32)) + sane(ldE(tg_[g], w, f32));
    }
    float h = sane(ldE(hx, bglob * 8 + w, f32));
    float c = sane(ldE(cx, bglob * 8 + w, f32));

    auto cumprod8 = [&](float e) {
        { float v = dpp_f<0x111>(e); e = (w >= 1) ? e * v : e; }
        { float v = dpp_f<0x112>(e); e = (w >= 2) ? e * v : e; }
        { float v = dpp_f<0x114>(e); e = (w >= 4) ? e * v : e; }
        return e;
    };

    // staging: flat LDS float4 idx = lane + 64*i; lane-invariant (w2,bs),
    // tl = tl0 + 2*i  ->  global float4 offset = base + ch*512 + i*16.
    const float4* A4 = (const float4*)A;
    const int w2 = tid & 7, bs = (tid >> 3) & 3, tl0 = tid >> 5;
    const float4* srcb = A4
        + ((((long)(blockIdx.x * 4 + bs)) << 8 | tl0) << 3) + w2;
    auto stage = [&](int ch, int bufi) {
        const float4* s0 = srcb + ((long)ch << 9);
#pragma unroll
        for (int i = 0; i < 32; ++i) {
            __builtin_amdgcn_global_load_lds((GV*)(s0 + (i << 4)),
                                             (LV*)&Abuf[bufi][i << 6], 16, 0, 0);
        }
    };

    auto STEP = [&](int t, float4 a) {
        // h all-to-all via XOR-basis DPP (R8-verified bit-identical)
        float h0 = h;
        float h1 = dpp_f<0xB1>(h);
        float h2 = dpp_f<0x4E>(h);
        float h3 = dpp_f<0xB1>(h2);       // xor3
        float h7 = dpp_f<0x141>(h);
        float h6 = dpp_f<0xB1>(h7);       // xor6
        float h5 = dpp_f<0x4E>(h7);       // xor5
        float h4 = dpp_f<0xB1>(h5);       // xor4

        float angF, angI, angU, angO;
        {
            float d0, d1;
            d0 = fmaf(h0, Whm[0][0], a.x + bt[0]); d1 = h1 * Whm[0][1];
            d0 = fmaf(h2, Whm[0][2], d0); d1 = fmaf(h3, Whm[0][3], d1);
            d0 = fmaf(h4, Whm[0][4], d0); d1 = fmaf(h5, Whm[0][5], d1);
            d0 = fmaf(h6, Whm[0][6], d0); d1 = fmaf(h7, Whm[0][7], d1);
            angF = d0 + d1;
            d0 = fmaf(h0, Whm[1][0], a.y + bt[1]); d1 = h1 * Whm[1][1];
            d0 = fmaf(h2, Whm[1][2], d0); d1 = fmaf(h3, Whm[1][3], d1);
            d0 = fmaf(h4, Whm[1][4], d0); d1 = fmaf(h5, Whm[1][5], d1);
            d0 = fmaf(h6, Whm[1][6], d0); d1 = fmaf(h7, Whm[1][7], d1);
            angI = d0 + d1;
            d0 = fmaf(h0, Whm[2][0], a.z + bt[2]); d1 = h1 * Whm[2][1];
            d0 = fmaf(h2, Whm[2][2], d0); d1 = fmaf(h3, Whm[2][3], d1);
            d0 = fmaf(h4, Whm[2][4], d0); d1 = fmaf(h5, Whm[2][5], d1);
            d0 = fmaf(h6, Whm[2][6], d0); d1 = fmaf(h7, Whm[2][7], d1);
            angU = d0 + d1;
            d0 = fmaf(h0, Whm[3][0], a.w + bt[3]); d1 = h1 * Whm[3][1];
            d0 = fmaf(h2, Whm[3][2], d0); d1 = fmaf(h3, Whm[3][3], d1);
            d0 = fmaf(h4, Whm[3][4], d0); d1 = fmaf(h5, Whm[3][5], d1);
            d0 = fmaf(h6, Whm[3][6], d0); d1 = fmaf(h7, Whm[3][7], d1);
            angO = d0 + d1;
        }
        float Ef = cumprod8(__cosf(angF));
        float Ei = cumprod8(__cosf(angI));
        float Eu = cumprod8(__cosf(angU));
        float Eo = cumprod8(__cosf(angO));
        float vf = sigp(Ef), vi = sigp(Ei), vu = tanp(Eu), vo = sigp(Eo);
        c = fmaf(vf, c, vi * vu);
        h = vo * tanh_pade(c);            // |c| <= ~2.1 by gate bounds
        if (dup == 0)
            stE(out, (long)t * 2048 + bglob * 8 + w, h, f32);
    };

    // prologue: stage chunk 0, drain
    stage(0, 0);
    asm volatile("s_waitcnt vmcnt(0)" ::: "memory");

    const int rdbase = bsub * 8 + w;
    for (int ch = 0; ch < 4; ++ch) {
        const int cb = ch & 1;
        if (ch + 1 < 4) stage(ch + 1, cb ^ 1);   // in flight across the steps
#pragma unroll 4
        for (int s = 0; s < 64; ++s) {
            float4 a = Abuf[cb][s * 32 + rdbase];
            STEP(ch * 64 + s, a);
        }
        asm volatile("s_waitcnt vmcnt(0)" ::: "memory");   // next buf ready
    }
    if (dup == 0) {
        stE(out, 524288L + bglob * 8 + w, h, f32);   // hT
        stE(out, 526336L + bglob * 8 + w, c, f32);   // cT
    }
}

// ================= v6 fallback (ws too small): proven at 140us =================
__global__ __launch_bounds__(320, 1) void qlstm_fused_v6(
    const void* __restrict__ X,  const void* __restrict__ hx, const void* __restrict__ cx,
    const void* __restrict__ Wf, const void* __restrict__ bf_,
    const void* __restrict__ Wi, const void* __restrict__ bi_,
    const void* __restrict__ Wu, const void* __restrict__ bu_,
    const void* __restrict__ Wo, const void* __restrict__ bo_,
    const void* __restrict__ tf, const void* __restrict__ ti,
    const void* __restrict__ tu, const void* __restrict__ to_,
    void* __restrict__ out)
{
    __shared__ float As4[2][4][32][32];

    const int tid = threadIdx.x;
    const int b   = blockIdx.x;
    const bool f32 = sniff_f32(X) != 0;

    const int wv   = tid >> 6;
    const int lane = tid & 63;
    const int kv   = wv - 1;
    const int o    = lane & 31;
    const int th   = lane >> 5;
    const int g    = o >> 3, w = o & 7;
    const void* Wg = (g == 0) ? Wf : (g == 1) ? Wi : (g == 2) ? Wu : Wo;

    float4 wreg[16];
    if (wv >= 1) {
        if (f32) {
            const float4* wr = (const float4*)((const float*)Wg + w * FAN + kv * 64);
#pragma unroll
            for (int i = 0; i < 16; ++i) wreg[i] = wr[i];
        } else {
            const uint4* wr = (const uint4*)((const unsigned short*)Wg + w * FAN + kv * 64);
#pragma unroll
            for (int i = 0; i < 8; ++i) {
                uint4 wu = wr[i];
                wreg[2 * i + 0] = make_float4(lo16f(wu.x), hi16f(wu.x),
                                              lo16f(wu.y), hi16f(wu.y));
                wreg[2 * i + 1] = make_float4(lo16f(wu.z), hi16f(wu.z),
                                              lo16f(wu.w), hi16f(wu.w));
            }
        }
    }

    auto fill = [&](int ch) {
        float (*dst)[32] = As4[ch & 1][kv];
        const int tb = ch * 32 + th * 16;
        if (f32) {
            for (int j = 0; j < 16; ++j) {
                const float4* xr = (const float4*)((const float*)X
                        + ((long)(tb + j) * BATCH + b) * DIMK + kv * 64);
                float a0 = 0.f, a1 = 0.f, a2 = 0.f, a3 = 0.f;
#pragma unroll
                for (int i = 0; i < 16; ++i) {
                    float4 xu = xr[i];
                    a0 = fmaf(xu.x, wreg[i].x, a0);
                    a1 = fmaf(xu.y, wreg[i].y, a1);
                    a2 = fmaf(xu.z, wreg[i].z, a2);
                    a3 = fmaf(xu.w, wreg[i].w, a3);
                }
                dst[th * 16 + j][o] = sane((a0 + a1) + (a2 + a3));
            }
        } else {
            for (int j = 0; j < 16; ++j) {
                const uint4* xr = (const uint4*)((const unsigned short*)X
                        + ((long)(tb + j) * BATCH + b) * DIMK + kv * 64);
                float a0 = 0.f, a1 = 0.f, a2 = 0.f, a3 = 0.f;
#pragma unroll
                for (int i = 0; i < 8; ++i) {
                    uint4 xu = xr[i];
                    a0 = fmaf(lo16f(xu.x), wreg[2 * i].x, a0);
                    a1 = fmaf(hi16f(xu.x), wreg[2 * i].y, a1);
                    a2 = fmaf(lo16f(xu.y), wreg[2 * i].z, a2);
                    a3 = fmaf(hi16f(xu.y), wreg[2 * i].w, a3);
                    a0 = fmaf(lo16f(xu.z), wreg[2 * i + 1].x, a0);
                    a1 = fmaf(hi16f(xu.z), wreg[2 * i + 1].y, a1);
                    a2 = fmaf(lo16f(xu.w), wreg[2 * i + 1].z, a2);
                    a3 = fmaf(hi16f(xu.w), wreg[2 * i + 1].w, a3);
                }
                dst[th * 16 + j][o] = sane((a0 + a1) + (a2 + a3));
            }
        }
    };

    float Wh[8];
    float bt = 0.f, h = 0.f, c = 0.f, qv = 1.f;
    int rw = 0, rg = 0;
    if (tid < 32) {
        rw = tid & 7; rg = tid >> 3;
        const void* bg = (rg == 0) ? bf_ : (rg == 1) ? bi_ : (rg == 2) ? bu_ : bo_;
        const void* tg = (rg == 0) ? tf  : (rg == 1) ? ti  : (rg == 2) ? tu  : to_;
        const int wr = rw * FAN;
#pragma unroll
        for (int j = 0; j < 8; ++j)
            Wh[j] = sane(ldE(Wg, wr + DIMK + j, f32));
        bt = sane(ldE(bg, rw, f32)) + sane(ldE(tg, rw, f32));
        h  = sane(ldE(hx, b * 8 + rw, f32));
        c  = sane(ldE(cx, b * 8 + rw, f32));
        qv = (rg == 2) ? 2.f : 1.f;
    }
    if (wv == 0) __builtin_amdgcn_s_setprio(1);

    if (wv >= 1) fill(0);
    __syncthreads();

    for (int ch = 0; ch < 8; ++ch) {
        if (wv >= 1 && ch + 1 < 8) fill(ch + 1);
        if (tid < 32) {
            const int buf = ch & 1;
            float n0 = As4[buf][0][0][tid], n1 = As4[buf][1][0][tid];
            float n2 = As4[buf][2][0][tid], n3 = As4[buf][3][0][tid];
            float a_cur = (n0 + n1) + (n2 + n3);
            for (int s = 0; s < 32; ++s) {
                const int sn = (s < 31) ? s + 1 : s;
                float m0 = As4[buf][0][sn][tid], m1 = As4[buf][1][sn][tid];
                float m2 = As4[buf][2][sn][tid], m3 = As4[buf][3][sn][tid];
                float d0 = 0.f, d1 = 0.f;
#pragma unroll
                for (int j = 0; j < 8; j += 2) {
                    d0 = fmaf(rdlane_f(h, j),     Wh[j],     d0);
                    d1 = fmaf(rdlane_f(h, j + 1), Wh[j + 1], d1);
                }
                float ang = a_cur + bt + (d0 + d1);
                float e = __cosf(ang);
                { float v = dpp_f<0x111>(e); e = (rw >= 1) ? e * v : e; }
                { float v = dpp_f<0x112>(e); e = (rw >= 2) ? e * v : e; }
                { float v = dpp_f<0x114>(e); e = (rw >= 4) ? e * v : e; }
                float ez  = __expf(qv * e);
                float val = 1.f - __fdividef(qv, ez + 1.f);
                float fg = swz_f<0x007>(val);
                float ig = swz_f<0x107>(val);
                float ug = swz_f<0x207>(val);
                float og = swz_f<0x307>(val);
                c = fmaf(fg, c, ig * ug);
                float e2 = __expf(2.f * c);
                float th2 = 1.f - __fdividef(2.f, e2 + 1.f);
                h = og * th2;
                if (rg == 0)
                    stE(out, (long)(ch * 32 + s) * 2048 + b * 8 + rw, h, f32);
                a_cur = (m0 + m1) + (m2 + m3);
            }
        }
        __syncthreads();
    }

    if (tid < 32 && rg == 0) {
        stE(out, 524288L + b * 8 + rw, h, f32);
        stE(out, 526336L + b * 8 + rw, c, f32);
    }
}

extern "C" void kernel_launch(void* const* d_in, const int* in_sizes, int n_in,
                              void* d_out, int out_size, void* d_ws, size_t ws_size,
                              hipStream_t stream) {
    if (d_ws != nullptr && ws_size >= WS_NEED) {
        qlstm_gemm<<<dim3(NROWS / 64), dim3(512), 0, stream>>>(
            d_in[0], d_in[3], d_in[5], d_in[7], d_in[9], (float*)d_ws);
        qlstm_rec<<<dim3(BATCH / 4), dim3(64), 0, stream>>>(
            d_in[0], d_in[1], d_in[2],
            d_in[3], d_in[4], d_in[5], d_in[6],
            d_in[7], d_in[8], d_in[9], d_in[10],
            d_in[11], d_in[12], d_in[13], d_in[14],
            d_out, (const float*)d_ws);
    } else {
        qlstm_fused_v6<<<dim3(BATCH), dim3(320), 0, stream>>>(
            d_in[0], d_in[1], d_in[2],
            d_in[3], d_in[4], d_in[5], d_in[6],
            d_in[7], d_in[8], d_in[9], d_in[10],
            d_in[11], d_in[12], d_in[13], d_in[14],
            d_out);
    }
}

// Round 11
// 207.201 us; speedup vs baseline: 1.3757x; 1.3757x over previous
//
#include <hip/hip_runtime.h>

// HybridQLSTMQuantum, MI355X — v11.
//   K1: GEMM with global_load_lds X staging (deep queue hides ~900cyc HBM
//       latency; v10's 2-deep reg pipeline covered only ~100cyc). Bias+theta
//       folded into A at writeout.
//   K2: recurrence with 2-WAY GATE SPLIT: lanes p<8 compute F,I; lanes p>=8
//       compute U,O (v10's dup half did identical work). One DPP row_ror:8
//       pair exchanges gate values. ~70 VALU/step vs ~140 (issue-bound at
//       1 wave/SIMD: VALUBusy said ~58% of the active SIMD was issue).
//
// qgate identity (verified analytically):
//   qgate(angles)[w] = prod_{j<=w} cos(angles[j])
//
// v6 single-kernel fallback retained for small ws.

#define S_LEN 256
#define BATCH 256
#define DIMK  256
#define FAN   264
#define NROWS (S_LEN * BATCH)
#define WS_NEED ((size_t)NROWS * 32 * 4)

typedef __attribute__((address_space(1))) const void GV;
typedef __attribute__((address_space(3))) void LV;

__device__ __forceinline__ float lo16f(unsigned u) {
    union { unsigned u; float f; } v; v.u = u << 16; return v.f;
}
__device__ __forceinline__ float hi16f(unsigned u) {
    union { unsigned u; float f; } v; v.u = u & 0xffff0000u; return v.f;
}
__device__ __forceinline__ float b2f(unsigned short u) {
    union { unsigned u; float f; } v; v.u = ((unsigned)u) << 16; return v.f;
}
__device__ __forceinline__ unsigned short f2b(float f) {
    union { float f; unsigned u; } v; v.f = f;
    unsigned r = v.u + 0x7fffu + ((v.u >> 16) & 1u);  // RNE
    return (unsigned short)(r >> 16);
}
__device__ __forceinline__ float sane(float x) {
    return (__builtin_fabsf(x) < 1e30f) ? x : 0.f;   // NaN compares false -> 0
}
__device__ __forceinline__ float ldE(const void* p, int idx, bool f32) {
    return f32 ? ((const float*)p)[idx] : b2f(((const unsigned short*)p)[idx]);
}
__device__ __forceinline__ void stE(void* p, long idx, float v, bool f32) {
    if (f32) ((float*)p)[idx] = v;
    else     ((unsigned short*)p)[idx] = f2b(v);
}
// poly sigmoid on [-1,1]: err<=1e-4 (R9-verified)
__device__ __forceinline__ float sigp(float x) {
    float x2 = x * x;
    float p = fmaf(x2, 0.0026216f, -0.0217557f);
    p = fmaf(x2, p, 0.250193f);
    return fmaf(x, p, 0.5f);
}
// Pade(5,4) tanh: err<=1e-4 for |x|<=2.2 (|c|<=~2.07 by gate bounds)
__device__ __forceinline__ float tanh_pade(float x) {
    float x2 = x * x;
    float num = x * fmaf(x2, x2 + 105.f, 945.f);
    float den = fmaf(x2, fmaf(x2, 15.f, 420.f), 945.f);
    return __fdividef(num, den);
}
__device__ __forceinline__ float tanh_f(float x) {   // exp-based (fallback kernel)
    return 1.f - __fdividef(2.f, __expf(2.f * x) + 1.f);
}

// DPP: 0x00-0xFF quad_perm; 0x110|K row_shr:K; 0x120|K row_ror:K; 0x141 half_mirror.
template<int CTRL>
__device__ __forceinline__ float dpp_f(float x) {
    int xi = __builtin_bit_cast(int, x);
    int r = __builtin_amdgcn_update_dpp(xi, xi, CTRL, 0xF, 0xF, false);
    return __builtin_bit_cast(float, r);
}
template<int IMM>
__device__ __forceinline__ float swz_f(float x) {
    return __builtin_bit_cast(float,
        __builtin_amdgcn_ds_swizzle(__builtin_bit_cast(int, x), IMM));
}
__device__ __forceinline__ float rdlane_f(float x, int l) {
    return __builtin_bit_cast(float,
        __builtin_amdgcn_readlane(__builtin_bit_cast(int, x), l));
}

__device__ __forceinline__ int sniff_f32(const void* X) {
    const unsigned short* u = (const unsigned short*)X;
    int hits = 0;
    for (int i = 0; i < 64; ++i) {
        int e = (u[2 * i] >> 7) & 0xFF;
        if (e >= 110 && e <= 135) ++hits;
    }
    return (hits < 32) ? 1 : 0;
}

// ============================ K1: GEMM -> ws ============================
// 512 thr = 8 waves; wave kv owns k in [kv*32,kv*32+32). Two 32-row chunks:
//   stage: 4 global_load_lds/lane -> Xs[kv] (deep queue, one vmcnt drain)
//   compute: dots from LDS (broadcast reads) with W in registers
//   reduce: 8 k-partials + bias+theta fold -> A[(row)*32 + w*4 + g]
__global__ __launch_bounds__(512, 4) void qlstm_gemm(
    const void* __restrict__ X,
    const void* __restrict__ Wf, const void* __restrict__ Wi,
    const void* __restrict__ Wu, const void* __restrict__ Wo,
    const void* __restrict__ bf_, const void* __restrict__ bi_,
    const void* __restrict__ bu_, const void* __restrict__ bo_,
    const void* __restrict__ tf, const void* __restrict__ ti,
    const void* __restrict__ tu, const void* __restrict__ to_,
    float* __restrict__ A)
{
    __shared__ float Xs[8][32][32];    // 32 KiB: [kv][row][k-local]
    __shared__ float red[8][32][32];   // 32 KiB k-partials

    const int tid = threadIdx.x;
    const bool f32 = sniff_f32(X) != 0;

    const int kv = tid >> 6;        // wave = k-slice (0..7)
    const int l  = tid & 63;
    const int o  = l & 31;
    const int th = l >> 5;          // row-half
    const int g  = o >> 3, w = o & 7;
    const void* Wg = (g == 0) ? Wf : (g == 1) ? Wi : (g == 2) ? Wu : Wo;
    const void* bg_[4] = { bf_, bi_, bu_, bo_ };
    const void* tg_[4] = { tf, ti, tu, to_ };

    float4 wreg[8];
    if (f32) {
        const float4* wr = (const float4*)((const float*)Wg + w * FAN + kv * 32);
#pragma unroll
        for (int i = 0; i < 8; ++i) wreg[i] = wr[i];
    } else {
        const uint4* wr = (const uint4*)((const unsigned short*)Wg + w * FAN + kv * 32);
#pragma unroll
        for (int i = 0; i < 4; ++i) {
            uint4 wu = wr[i];
            wreg[2 * i + 0] = make_float4(lo16f(wu.x), hi16f(wu.x),
                                          lo16f(wu.y), hi16f(wu.y));
            wreg[2 * i + 1] = make_float4(lo16f(wu.z), hi16f(wu.z),
                                          lo16f(wu.w), hi16f(wu.w));
        }
    }

    const long rowbase = (long)blockIdx.x * 64;   // rows = b*256 + t

    for (int chunk = 0; chunk < 2; ++chunk) {
        if (f32) {
            // ---- stage 32 rows x 32 k into Xs[kv] via global_load_lds.
            // issue i: lane l -> row i*8 + (l>>3), k-local (l&7)*4;
            // LDS dest = &Xs[kv][i*8][0] + l*16B (HW lane spread) = same slot.
#pragma unroll
            for (int i = 0; i < 4; ++i) {
                const long row = rowbase + chunk * 32 + i * 8 + (l >> 3);
                const int t = (int)(row & 255), bb = (int)(row >> 8);
                const float* src = (const float*)X
                        + ((long)t * BATCH + bb) * DIMK + kv * 32 + (l & 7) * 4;
                __builtin_amdgcn_global_load_lds((GV*)src,
                        (LV*)&Xs[kv][i * 8][0], 16, 0, 0);
            }
            asm volatile("s_waitcnt vmcnt(0)" ::: "memory");  // Xs[kv] wave-local
            // ---- compute 16 rows per lane-half from LDS (broadcast reads)
            for (int j = 0; j < 16; ++j) {
                const int r = th * 16 + j;
                const float4* xv = (const float4*)&Xs[kv][r][0];
                float a0 = 0.f, a1 = 0.f, a2 = 0.f, a3 = 0.f;
#pragma unroll
                for (int i = 0; i < 8; ++i) {
                    float4 xu = xv[i];
                    a0 = fmaf(xu.x, wreg[i].x, a0);
                    a1 = fmaf(xu.y, wreg[i].y, a1);
                    a2 = fmaf(xu.z, wreg[i].z, a2);
                    a3 = fmaf(xu.w, wreg[i].w, a3);
                }
                red[kv][r][o] = (a0 + a1) + (a2 + a3);
            }
        } else {
            // bf16 path: global loads (dots as v10); never taken in practice
            for (int j = 0; j < 16; ++j) {
                const int r = th * 16 + j;
                const long row = rowbase + chunk * 32 + r;
                const int t = (int)(row & 255), bb = (int)(row >> 8);
                const uint4* xr = (const uint4*)((const unsigned short*)X
                        + ((long)t * BATCH + bb) * DIMK + kv * 32);
                float a0 = 0.f, a1 = 0.f, a2 = 0.f, a3 = 0.f;
#pragma unroll
                for (int i = 0; i < 4; ++i) {
                    uint4 xu = xr[i];
                    a0 = fmaf(lo16f(xu.x), wreg[2 * i].x, a0);
                    a1 = fmaf(hi16f(xu.x), wreg[2 * i].y, a1);
                    a2 = fmaf(lo16f(xu.y), wreg[2 * i].z, a2);
                    a3 = fmaf(hi16f(xu.y), wreg[2 * i].w, a3);
                    a0 = fmaf(lo16f(xu.z), wreg[2 * i + 1].x, a0);
                    a1 = fmaf(hi16f(xu.z), wreg[2 * i + 1].y, a1);
                    a2 = fmaf(lo16f(xu.w), wreg[2 * i + 1].z, a2);
                    a3 = fmaf(hi16f(xu.w), wreg[2 * i + 1].w, a3);
                }
                red[kv][r][o] = (a0 + a1) + (a2 + a3);
            }
        }
        __syncthreads();
        // ---- reduce 8 k-partials, fold bias+theta, repack col = w*4+g
        for (int idx = tid; idx < 32 * 32; idx += 512) {
            const int rl = idx >> 5, oo = idx & 31;
            float s = 0.f;
#pragma unroll
            for (int k = 0; k < 8; ++k) s += red[k][rl][oo];
            const int g2 = oo >> 3, w2 = oo & 7;
            const float bt = sane(ldE(bg_[g2], w2, f32))
                           + sane(ldE(tg_[g2], w2, f32));
            A[(rowbase + chunk * 32 + rl) * 32 + w2 * 4 + g2] = sane(s) + bt;
        }
        __syncthreads();   // red/Xs reusable next chunk
    }
}

// ========================= K2: recurrence (2-way gate split) =========================
// 64 blocks x 64 thr; wave = 4 b-rows x 16 lanes. Lane p = w(0..7) x half.
// half0 computes gates F,I; half1 computes U,O. Exchange via DPP row_ror:8.
// A (bias pre-folded) staged via global_load_lds, 2x32KB double buffer.
__global__ __launch_bounds__(64) void qlstm_rec(
    const void* __restrict__ X,  const void* __restrict__ hx, const void* __restrict__ cx,
    const void* __restrict__ Wf, const void* __restrict__ Wi,
    const void* __restrict__ Wu, const void* __restrict__ Wo,
    void* __restrict__ out, const float* __restrict__ A)
{
    __shared__ float4 Abuf[2][2048];   // 64 KiB: [buf][t_loc*32 + bsub*8 + w]

    const int tid = threadIdx.x;
    const bool f32 = sniff_f32(X) != 0;

    const int p     = tid & 15;        // position in 16-lane row (one b)
    const int w     = p & 7;           // wire
    const int half  = p >> 3;          // 0: F,I ; 1: U,O
    const int bsub  = tid >> 4;        // 0..3
    const int bglob = blockIdx.x * 4 + bsub;

    // gate pair for this half
    const void* WgA = half ? Wu : Wf;
    const void* WgB = half ? Wo : Wi;

    // XOR-permuted h-coefficients: Wh*[m] pairs with h_{w^m}
    float WhA[8], WhB[8];
#pragma unroll
    for (int m = 0; m < 8; ++m) {
        WhA[m] = sane(ldE(WgA, w * FAN + DIMK + (w ^ m), f32));
        WhB[m] = sane(ldE(WgB, w * FAN + DIMK + (w ^ m), f32));
    }
    // unified first-gate nonlinearity: v = s0 + x*(d0 + x2*(d1 + x2*(d2 + x2*d3)))
    // half0 -> sigmoid coeffs, half1 -> tanh coeffs (both err<=2e-4 on [-1,1])
    const float d3 = half ? -0.028402f : 0.f;
    const float d2 = half ?  0.121713f : 0.0026216f;
    const float d1 = half ? -0.331717f : -0.0217557f;
    const float d0 = half ?  1.0f      : 0.250193f;
    const float s0 = half ?  0.f       : 0.5f;

    float h = sane(ldE(hx, bglob * 8 + w, f32));
    float c = sane(ldE(cx, bglob * 8 + w, f32));

    auto cumprod8 = [&](float e) {
        { float v = dpp_f<0x111>(e); e = (w >= 1) ? e * v : e; }
        { float v = dpp_f<0x112>(e); e = (w >= 2) ? e * v : e; }
        { float v = dpp_f<0x114>(e); e = (w >= 4) ? e * v : e; }
        return e;
    };

    // staging (v10-verified): LDS float4 idx = lane + 64*i
    const float4* A4 = (const float4*)A;
    const int w2 = tid & 7, bs = (tid >> 3) & 3, tl0 = tid >> 5;
    const float4* srcb = A4
        + ((((long)(blockIdx.x * 4 + bs)) << 8 | tl0) << 3) + w2;
    auto stage = [&](int ch, int bufi) {
        const float4* s0p = srcb + ((long)ch << 9);
#pragma unroll
        for (int i = 0; i < 32; ++i) {
            __builtin_amdgcn_global_load_lds((GV*)(s0p + (i << 4)),
                                             (LV*)&Abuf[bufi][i << 6], 16, 0, 0);
        }
    };

    auto STEP = [&](int t, float aA, float aB) {
        // h all-to-all within 8-group via XOR-basis DPP
        float h0 = h;
        float h1 = dpp_f<0xB1>(h);
        float h2 = dpp_f<0x4E>(h);
        float h3 = dpp_f<0xB1>(h2);       // xor3
        float h7 = dpp_f<0x141>(h);
        float h6 = dpp_f<0xB1>(h7);       // xor6
        float h5 = dpp_f<0x4E>(h7);       // xor5
        float h4 = dpp_f<0xB1>(h5);       // xor4

        float e0, e1;
        {
            float a = fmaf(h0, WhA[0], aA), b = h1 * WhA[1];
            a = fmaf(h2, WhA[2], a); b = fmaf(h3, WhA[3], b);
            a = fmaf(h4, WhA[4], a); b = fmaf(h5, WhA[5], b);
            a = fmaf(h6, WhA[6], a); b = fmaf(h7, WhA[7], b);
            e0 = a + b;
            a = fmaf(h0, WhB[0], aB); b = h1 * WhB[1];
            a = fmaf(h2, WhB[2], a); b = fmaf(h3, WhB[3], b);
            a = fmaf(h4, WhB[4], a); b = fmaf(h5, WhB[5], b);
            a = fmaf(h6, WhB[6], a); b = fmaf(h7, WhB[7], b);
            e1 = a + b;
        }
        float EA = cumprod8(__cosf(e0));
        float EB = cumprod8(__cosf(e1));
        // vA: unified per-half poly (F->sigm / U->tanh); vB: sigmoid (I and O)
        float x2 = EA * EA;
        float pp = fmaf(x2, d3, d2);
        pp = fmaf(x2, pp, d1);
        pp = fmaf(x2, pp, d0);
        float vA = fmaf(EA, pp, s0);
        float vB = sigp(EB);
        // exchange across halves (same w): lane p <-> p^8 via row_ror:8
        float rA = dpp_f<0x128>(vA);
        float rB = dpp_f<0x128>(vB);
        float vf = half ? rA : vA;
        float vi = half ? rB : vB;
        float vu = half ? vA : rA;
        float vo = half ? vB : rB;
        c = fmaf(vf, c, vi * vu);
        h = vo * tanh_pade(c);
        if (half == 0)
            stE(out, (long)t * 2048 + bglob * 8 + w, h, f32);
    };

    // prologue: stage chunk 0, drain
    stage(0, 0);
    asm volatile("s_waitcnt vmcnt(0)" ::: "memory");

    const float2* Ab2 = (const float2*)&Abuf[0][0];
    const int rdbase = (bsub * 8 + w) * 2 + half;   // float2 units
    for (int ch = 0; ch < 4; ++ch) {
        const int cb = ch & 1;
        if (ch + 1 < 4) stage(ch + 1, cb ^ 1);   // in flight across steps
#pragma unroll 4
        for (int s = 0; s < 64; ++s) {
            float2 a = Ab2[cb * 4096 + s * 64 + rdbase];
            STEP(ch * 64 + s, a.x, a.y);
        }
        asm volatile("s_waitcnt vmcnt(0)" ::: "memory");   // next buf ready
    }
    if (half == 0) {
        stE(out, 524288L + bglob * 8 + w, h, f32);   // hT
        stE(out, 526336L + bglob * 8 + w, c, f32);   // cT
    }
}

// ================= v6 fallback (ws too small): proven at 140us =================
__global__ __launch_bounds__(320, 1) void qlstm_fused_v6(
    const void* __restrict__ X,  const void* __restrict__ hx, const void* __restrict__ cx,
    const void* __restrict__ Wf, const void* __restrict__ bf_,
    const void* __restrict__ Wi, const void* __restrict__ bi_,
    const void* __restrict__ Wu, const void* __restrict__ bu_,
    const void* __restrict__ Wo, const void* __restrict__ bo_,
    const void* __restrict__ tf, const void* __restrict__ ti,
    const void* __restrict__ tu, const void* __restrict__ to_,
    void* __restrict__ out)
{
    __shared__ float As4[2][4][32][32];

    const int tid = threadIdx.x;
    const int b   = blockIdx.x;
    const bool f32 = sniff_f32(X) != 0;

    const int wv   = tid >> 6;
    const int lane = tid & 63;
    const int kv   = wv - 1;
    const int o    = lane & 31;
    const int th   = lane >> 5;
    const int g    = o >> 3, w = o & 7;
    const void* Wg = (g == 0) ? Wf : (g == 1) ? Wi : (g == 2) ? Wu : Wo;

    float4 wreg[16];
    if (wv >= 1) {
        if (f32) {
            const float4* wr = (const float4*)((const float*)Wg + w * FAN + kv * 64);
#pragma unroll
            for (int i = 0; i < 16; ++i) wreg[i] = wr[i];
        } else {
            const uint4* wr = (const uint4*)((const unsigned short*)Wg + w * FAN + kv * 64);
#pragma unroll
            for (int i = 0; i < 8; ++i) {
                uint4 wu = wr[i];
                wreg[2 * i + 0] = make_float4(lo16f(wu.x), hi16f(wu.x),
                                              lo16f(wu.y), hi16f(wu.y));
                wreg[2 * i + 1] = make_float4(lo16f(wu.z), hi16f(wu.z),
                                              lo16f(wu.w), hi16f(wu.w));
            }
        }
    }

    auto fill = [&](int ch) {
        float (*dst)[32] = As4[ch & 1][kv];
        const int tb = ch * 32 + th * 16;
        if (f32) {
            for (int j = 0; j < 16; ++j) {
                const float4* xr = (const float4*)((const float*)X
                        + ((long)(tb + j) * BATCH + b) * DIMK + kv * 64);
                float a0 = 0.f, a1 = 0.f, a2 = 0.f, a3 = 0.f;
#pragma unroll
                for (int i = 0; i < 16; ++i) {
                    float4 xu = xr[i];
                    a0 = fmaf(xu.x, wreg[i].x, a0);
                    a1 = fmaf(xu.y, wreg[i].y, a1);
                    a2 = fmaf(xu.z, wreg[i].z, a2);
                    a3 = fmaf(xu.w, wreg[i].w, a3);
                }
                dst[th * 16 + j][o] = sane((a0 + a1) + (a2 + a3));
            }
        } else {
            for (int j = 0; j < 16; ++j) {
                const uint4* xr = (const uint4*)((const unsigned short*)X
                        + ((long)(tb + j) * BATCH + b) * DIMK + kv * 64);
                float a0 = 0.f, a1 = 0.f, a2 = 0.f, a3 = 0.f;
#pragma unroll
                for (int i = 0; i < 8; ++i) {
                    uint4 xu = xr[i];
                    a0 = fmaf(lo16f(xu.x), wreg[2 * i].x, a0);
                    a1 = fmaf(hi16f(xu.x), wreg[2 * i].y, a1);
                    a2 = fmaf(lo16f(xu.y), wreg[2 * i].z, a2);
                    a3 = fmaf(hi16f(xu.y), wreg[2 * i].w, a3);
                    a0 = fmaf(lo16f(xu.z), wreg[2 * i + 1].x, a0);
                    a1 = fmaf(hi16f(xu.z), wreg[2 * i + 1].y, a1);
                    a2 = fmaf(lo16f(xu.w), wreg[2 * i + 1].z, a2);
                    a3 = fmaf(hi16f(xu.w), wreg[2 * i + 1].w, a3);
                }
                dst[th * 16 + j][o] = sane((a0 + a1) + (a2 + a3));
            }
        }
    };

    float Wh[8];
    float bt = 0.f, h = 0.f, c = 0.f, qv = 1.f;
    int rw = 0, rg = 0;
    if (tid < 32) {
        rw = tid & 7; rg = tid >> 3;
        const void* bg = (rg == 0) ? bf_ : (rg == 1) ? bi_ : (rg == 2) ? bu_ : bo_;
        const void* tg = (rg == 0) ? tf  : (rg == 1) ? ti  : (rg == 2) ? tu  : to_;
        const int wr = rw * FAN;
#pragma unroll
        for (int j = 0; j < 8; ++j)
            Wh[j] = sane(ldE(Wg, wr + DIMK + j, f32));
        bt = sane(ldE(bg, rw, f32)) + sane(ldE(tg, rw, f32));
        h  = sane(ldE(hx, b * 8 + rw, f32));
        c  = sane(ldE(cx, b * 8 + rw, f32));
        qv = (rg == 2) ? 2.f : 1.f;
    }
    if (wv == 0) __builtin_amdgcn_s_setprio(1);

    if (wv >= 1) fill(0);
    __syncthreads();

    for (int ch = 0; ch < 8; ++ch) {
        if (wv >= 1 && ch + 1 < 8) fill(ch + 1);
        if (tid < 32) {
            const int buf = ch & 1;
            float n0 = As4[buf][0][0][tid], n1 = As4[buf][1][0][tid];
            float n2 = As4[buf][2][0][tid], n3 = As4[buf][3][0][tid];
            float a_cur = (n0 + n1) + (n2 + n3);
            for (int s = 0; s < 32; ++s) {
                const int sn = (s < 31) ? s + 1 : s;
                float m0 = As4[buf][0][sn][tid], m1 = As4[buf][1][sn][tid];
                float m2 = As4[buf][2][sn][tid], m3 = As4[buf][3][sn][tid];
                float dd0 = 0.f, dd1 = 0.f;
#pragma unroll
                for (int j = 0; j < 8; j += 2) {
                    dd0 = fmaf(rdlane_f(h, j),     Wh[j],     dd0);
                    dd1 = fmaf(rdlane_f(h, j + 1), Wh[j + 1], dd1);
                }
                float ang = a_cur + bt + (dd0 + dd1);
                float e = __cosf(ang);
                { float v = dpp_f<0x111>(e); e = (rw >= 1) ? e * v : e; }
                { float v = dpp_f<0x112>(e); e = (rw >= 2) ? e * v : e; }
                { float v = dpp_f<0x114>(e); e = (rw >= 4) ? e * v : e; }
                float ez  = __expf(qv * e);
                float val = 1.f - __fdividef(qv, ez + 1.f);
                float fg = swz_f<0x007>(val);
                float ig = swz_f<0x107>(val);
                float ug = swz_f<0x207>(val);
                float og = swz_f<0x307>(val);
                c = fmaf(fg, c, ig * ug);
                float e2 = __expf(2.f * c);
                float th2 = 1.f - __fdividef(2.f, e2 + 1.f);
                h = og * th2;
                if (rg == 0)
                    stE(out, (long)(ch * 32 + s) * 2048 + b * 8 + rw, h, f32);
                a_cur = (m0 + m1) + (m2 + m3);
            }
        }
        __syncthreads();
    }

    if (tid < 32 && rg == 0) {
        stE(out, 524288L + b * 8 + rw, h, f32);
        stE(out, 526336L + b * 8 + rw, c, f32);
    }
}

extern "C" void kernel_launch(void* const* d_in, const int* in_sizes, int n_in,
                              void* d_out, int out_size, void* d_ws, size_t ws_size,
                              hipStream_t stream) {
    if (d_ws != nullptr && ws_size >= WS_NEED) {
        qlstm_gemm<<<dim3(NROWS / 64), dim3(512), 0, stream>>>(
            d_in[0], d_in[3], d_in[5], d_in[7], d_in[9],
            d_in[4], d_in[6], d_in[8], d_in[10],
            d_in[11], d_in[12], d_in[13], d_in[14],
            (float*)d_ws);
        qlstm_rec<<<dim3(BATCH / 4), dim3(64), 0, stream>>>(
            d_in[0], d_in[1], d_in[2],
            d_in[3], d_in[5], d_in[7], d_in[9],
            d_out, (const float*)d_ws);
    } else {
        qlstm_fused_v6<<<dim3(BATCH), dim3(320), 0, stream>>>(
            d_in[0], d_in[1], d_in[2],
            d_in[3], d_in[4], d_in[5], d_in[6],
            d_in[7], d_in[8], d_in[9], d_in[10],
            d_in[11], d_in[12], d_in[13], d_in[14],
            d_out);
    }
}